// Round 1
// baseline (16650.143 us; speedup 1.0000x reference)
//
#include <hip/hip_runtime.h>

// Problem constants
#define Bz 16
#define Gc 30
#define Hs 24
#define Wd_ 862
#define HW (Hs*Wd_)          // 20688
#define BHW (Bz*HW)          // 331008
#define NPAIR (BHW/2)        // 165504
#define PREN 720

__device__ __forceinline__ int imin(int a,int b){return a<b?a:b;}
__device__ __forceinline__ int imax(int a,int b){return a>b?a:b;}

struct Corners { float m00,m01,m10,m11; int i00,i01,i10,i11; };

__device__ __forceinline__ Corners mk_corners(float py, float px){
  float y0f = floorf(py), x0f = floorf(px);
  float wy = py - y0f, wx = px - x0f;
  int y0 = (int)y0f, x0 = (int)x0f;
  int y1 = y0 + 1, x1 = x0 + 1;
  bool y0i = ((unsigned)y0 < (unsigned)Hs);
  bool y1i = ((unsigned)y1 < (unsigned)Hs);
  bool x0i = ((unsigned)x0 < (unsigned)Wd_);
  bool x1i = ((unsigned)x1 < (unsigned)Wd_);
  float w00=(1.f-wy)*(1.f-wx), w01=(1.f-wy)*wx, w10=wy*(1.f-wx), w11=wy*wx;
  Corners c;
  c.m00 = (y0i&&x0i)?w00:0.f; c.m01=(y0i&&x1i)?w01:0.f;
  c.m10 = (y1i&&x0i)?w10:0.f; c.m11=(y1i&&x1i)?w11:0.f;
  int y0c=imin(imax(y0,0),Hs-1), y1c=imin(imax(y1,0),Hs-1);
  int x0c=imin(imax(x0,0),Wd_-1), x1c=imin(imax(x1,0),Wd_-1);
  c.i00=y0c*Wd_+x0c; c.i01=y0c*Wd_+x1c; c.i10=y1c*Wd_+x0c; c.i11=y1c*Wd_+x1c;
  return c;
}

#define ACC8(acc, sv) (acc) += wa.x*(sv)[0]+wa.y*(sv)[1]+wa.z*(sv)[2]+wa.w*(sv)[3] \
                             + wb.x*(sv)[4]+wb.y*(sv)[5]+wb.z*(sv)[6]+wb.w*(sv)[7]

// ---------------- K1: group_inner = 1x1 conv over channel dim -------------
__global__ __launch_bounds__(256) void k_group_inner(
    const float* __restrict__ x, const float* __restrict__ Wbl,
    const float* __restrict__ bbl, float* __restrict__ out)
{
  __shared__ float w_s[Gc*32];   // [k][c32]
  __shared__ float b_s[Gc];
  for (int idx = threadIdx.x; idx < Gc*32; idx += 256){
    int k = idx >> 5, c = idx & 31;
    w_s[idx] = (c < Gc) ? Wbl[k*Gc + c] : 0.f;
  }
  if (threadIdx.x < Gc) b_s[threadIdx.x] = bbl[threadIdx.x];
  __syncthreads();
  long pair = (long)blockIdx.x*256 + threadIdx.x;
  if (pair >= (long)NPAIR) return;
  int b = (int)(pair / (HW/2));
  int s = (int)(pair % (HW/2)) * 2;
  const float* xb = x + (size_t)b*Gc*HW + s;
  float acc0[Gc], acc1[Gc];
  #pragma unroll
  for (int k=0;k<Gc;k++){ float bb=b_s[k]; acc0[k]=bb; acc1[k]=bb; }
  #pragma unroll
  for (int co=0; co<4; co++){
    float xv0[8], xv1[8];
    #pragma unroll
    for (int cc=0; cc<8; cc++){
      int c = co*8+cc;
      if (c < Gc){
        float2 v = *(const float2*)(xb + (size_t)c*HW);
        xv0[cc]=v.x; xv1[cc]=v.y;
      } else { xv0[cc]=0.f; xv1[cc]=0.f; }
    }
    #pragma unroll
    for (int k=0;k<Gc;k++){
      const float* wrow = &w_s[k*32 + co*8];
      float4 wa = *(const float4*)wrow; float4 wb = *(const float4*)(wrow+4);
      ACC8(acc0[k], xv0); ACC8(acc1[k], xv1);
    }
  }
  float* ob = out + (size_t)b*Gc*HW + s;
  #pragma unroll
  for (int k=0;k<Gc;k++){ ob[(size_t)k*HW]=acc0[k]; ob[(size_t)k*HW+1]=acc1[k]; }
}

// ---------------- K2/K5: 3x3 conv, 30 -> OC channels, dilation r ----------
template<int OC>
__global__ __launch_bounds__(256) void k_conv3x3(
    const float* __restrict__ x, const float* __restrict__ Wo,
    const float* __restrict__ bo, float* __restrict__ out, int r)
{
  __shared__ float w_s[9*OC*32];  // [ki][o][c32]
  for (int idx = threadIdx.x; idx < 9*OC*32; idx += 256){
    int ki = idx / (OC*32); int rem = idx % (OC*32);
    int o = rem >> 5; int c = rem & 31;
    w_s[idx] = (c < Gc) ? Wo[(o*Gc + c)*9 + ki] : 0.f;
  }
  __syncthreads();
  long pair = (long)blockIdx.x*256 + threadIdx.x;
  if (pair >= (long)NPAIR) return;
  int b = (int)(pair / (HW/2));
  int s = (int)(pair % (HW/2)) * 2;
  int h = s / Wd_, w = s % Wd_;
  const float* xb = x + (size_t)b*Gc*HW;
  float acc0[OC], acc1[OC];
  #pragma unroll
  for (int o=0;o<OC;o++){ float bb=bo[o]; acc0[o]=bb; acc1[o]=bb; }
  #pragma unroll
  for (int ki=0; ki<9; ki++){
    const int dy = ki/3 - 1, dx = ki%3 - 1;
    const int hh = h + dy*r;
    const bool hok = ((unsigned)hh < (unsigned)Hs);
    const int w0 = w + dx*r, w1 = w0 + 1;
    const bool ok0 = hok && ((unsigned)w0 < (unsigned)Wd_);
    const bool ok1 = hok && ((unsigned)w1 < (unsigned)Wd_);
    const float* xrow = xb + (long)hh*Wd_;
    #pragma unroll
    for (int co=0; co<4; co++){
      float xv0[8], xv1[8];
      #pragma unroll
      for (int cc=0; cc<8; cc++){
        int c = co*8+cc;
        if (c < Gc){
          const float* xc = xrow + (size_t)c*HW;
          xv0[cc] = ok0 ? xc[w0] : 0.f;
          xv1[cc] = ok1 ? xc[w1] : 0.f;
        } else { xv0[cc]=0.f; xv1[cc]=0.f; }
      }
      #pragma unroll
      for (int o=0;o<OC;o++){
        const float* wrow = &w_s[(ki*OC+o)*32 + co*8];
        float4 wa = *(const float4*)wrow; float4 wb = *(const float4*)(wrow+4);
        ACC8(acc0[o], xv0); ACC8(acc1[o], xv1);
      }
    }
  }
  float* ob = out + (size_t)b*OC*HW + s;
  #pragma unroll
  for (int o=0;o<OC;o++){ ob[(size_t)o*HW]=acc0[o]; ob[(size_t)o*HW+1]=acc1[o]; }
}

// ---------------- K3: deformable conv (sample + 30x30 matvec per tap) -----
__global__ __launch_bounds__(256) void k_deform(
    const float* __restrict__ x, const float* __restrict__ off,
    const float* __restrict__ Wdf, const float* __restrict__ bd,
    float* __restrict__ out, int r, int first)
{
  __shared__ float w_s[9*Gc*32];  // [ki][o][c32]
  for (int idx = threadIdx.x; idx < 9*Gc*32; idx += 256){
    int ki = idx / (Gc*32); int rem = idx % (Gc*32);
    int o = rem >> 5; int c = rem & 31;
    w_s[idx] = (c < Gc) ? Wdf[(o*Gc + c)*9 + ki] : 0.f;
  }
  __syncthreads();
  long pair = (long)blockIdx.x*256 + threadIdx.x;
  if (pair >= (long)NPAIR) return;
  int b = (int)(pair / (HW/2));
  int s = (int)(pair % (HW/2)) * 2;
  int h = s / Wd_, w = s % Wd_;
  const float* xb = x + (size_t)b*Gc*HW;
  const float* offb = off + (size_t)b*18*HW + s;
  float acc0[Gc], acc1[Gc];
  #pragma unroll
  for (int o=0;o<Gc;o++){ float bb=bd[o]; acc0[o]=bb; acc1[o]=bb; }
  #pragma unroll
  for (int ki=0; ki<9; ki++){
    const int dy = ki/3 - 1, dx = ki%3 - 1;
    float oy0 = offb[(size_t)(2*ki)*HW];
    float oy1 = offb[(size_t)(2*ki)*HW + 1];
    float ox0 = offb[(size_t)(2*ki+1)*HW];
    float ox1 = offb[(size_t)(2*ki+1)*HW + 1];
    Corners c0 = mk_corners(oy0 + (float)(h + dy*r), ox0 + (float)(w + dx*r));
    Corners c1 = mk_corners(oy1 + (float)(h + dy*r), ox1 + (float)(w + 1 + dx*r));
    #pragma unroll
    for (int co=0; co<4; co++){
      float sv0[8], sv1[8];
      #pragma unroll
      for (int cc=0; cc<8; cc++){
        int c = co*8+cc;
        if (c < Gc){
          const float* xc = xb + (size_t)c*HW;
          sv0[cc] = c0.m00*xc[c0.i00] + c0.m01*xc[c0.i01]
                  + c0.m10*xc[c0.i10] + c0.m11*xc[c0.i11];
          sv1[cc] = c1.m00*xc[c1.i00] + c1.m01*xc[c1.i01]
                  + c1.m10*xc[c1.i10] + c1.m11*xc[c1.i11];
        } else { sv0[cc]=0.f; sv1[cc]=0.f; }
      }
      #pragma unroll
      for (int o=0;o<Gc;o++){
        const float* wrow = &w_s[(ki*Gc+o)*32 + co*8];
        float4 wa = *(const float4*)wrow; float4 wb = *(const float4*)(wrow+4);
        ACC8(acc0[o], sv0); ACC8(acc1[o], sv1);
      }
    }
  }
  float* ob = out + (size_t)b*Gc*HW + s;
  if (first){
    #pragma unroll
    for (int o=0;o<Gc;o++){ ob[(size_t)o*HW]=acc0[o]; ob[(size_t)o*HW+1]=acc1[o]; }
  } else {
    #pragma unroll
    for (int o=0;o<Gc;o++){ ob[(size_t)o*HW]+=acc0[o]; ob[(size_t)o*HW+1]+=acc1[o]; }
  }
}

// ---------------- K4: repres = gi * (1 + softmax_c(mdef)), in-place on gi --
__global__ __launch_bounds__(256) void k_gate(
    const float* __restrict__ md, float* __restrict__ gi)
{
  long idx = (long)blockIdx.x*256 + threadIdx.x;
  if (idx >= (long)BHW) return;
  int b = (int)(idx / HW); int s = (int)(idx % HW);
  const float* m = md + (size_t)b*Gc*HW + s;
  float* g = gi + (size_t)b*Gc*HW + s;
  float v[Gc];
  float mx = -1e30f;
  #pragma unroll
  for (int c=0;c<Gc;c++){ v[c] = m[(size_t)c*HW]; mx = fmaxf(mx, v[c]); }
  float sum = 0.f;
  #pragma unroll
  for (int c=0;c<Gc;c++){ v[c] = __expf(v[c]-mx); sum += v[c]; }
  float inv = 1.f/sum;
  #pragma unroll
  for (int c=0;c<Gc;c++){
    float gv = g[(size_t)c*HW];
    g[(size_t)c*HW] = gv + gv*(v[c]*inv);
  }
}

// ---------------- K6: out[b,q,n] = sum_p Wp[q,p]*F[b,p,n] + bp[q] ---------
__global__ __launch_bounds__(256) void k_proj(
    const float* __restrict__ F, const float* __restrict__ Wp,
    const float* __restrict__ bp, float* __restrict__ out)
{
  __shared__ float As[16][68];   // [k][m] transposed, pad 68 (float4-aligned)
  __shared__ float Bs[16][64];   // [k][n]
  const int b = blockIdx.z;
  const int q0 = blockIdx.y*64;
  const int n0 = blockIdx.x*64;
  const int tid = threadIdx.x;
  const int tm = tid >> 4, tn = tid & 15;
  const int ar = tid >> 4, ac = tid & 15;
  const int br = tid >> 6, bc = tid & 63;
  const float* Fb = F + (size_t)b*PREN*Wd_;
  float acc[4][4] = {};
  for (int k0 = 0; k0 < PREN; k0 += 16){
    #pragma unroll
    for (int i=0;i<4;i++){
      int q = q0 + ar + 16*i;
      float v = (q < PREN) ? Wp[(size_t)q*PREN + k0 + ac] : 0.f;
      As[ac][ar + 16*i] = v;
    }
    #pragma unroll
    for (int i=0;i<4;i++){
      int p = k0 + br + 4*i;
      int n = n0 + bc;
      float v = (n < Wd_) ? Fb[(size_t)p*Wd_ + n] : 0.f;
      Bs[br + 4*i][bc] = v;
    }
    __syncthreads();
    #pragma unroll
    for (int k=0;k<16;k++){
      float4 a4 = *(const float4*)&As[k][tm*4];
      float4 b4 = *(const float4*)&Bs[k][tn*4];
      float av[4] = {a4.x,a4.y,a4.z,a4.w};
      float bv[4] = {b4.x,b4.y,b4.z,b4.w};
      #pragma unroll
      for (int i=0;i<4;i++)
        #pragma unroll
        for (int j=0;j<4;j++) acc[i][j] += av[i]*bv[j];
    }
    __syncthreads();
  }
  #pragma unroll
  for (int i=0;i<4;i++){
    int q = q0 + tm*4 + i;
    if (q >= PREN) continue;
    float bias = bp[q];
    #pragma unroll
    for (int j=0;j<4;j++){
      int n = n0 + tn*4 + j;
      if (n < Wd_) out[((size_t)b*PREN + q)*Wd_ + n] = acc[i][j] + bias;
    }
  }
}

extern "C" void kernel_launch(void* const* d_in, const int* in_sizes, int n_in,
                              void* d_out, int out_size, void* d_ws, size_t ws_size,
                              hipStream_t stream)
{
  (void)in_sizes; (void)n_in; (void)out_size; (void)ws_size;
  const float* x    = (const float*)d_in[0];
  const float* Wbl  = (const float*)d_in[1];
  const float* bbl  = (const float*)d_in[2];
  const float* Woff = (const float*)d_in[3];   // [2,18,30,3,3]
  const float* boff = (const float*)d_in[4];   // [2,18]
  const float* Wdef = (const float*)d_in[5];   // [2,30,30,3,3]
  const float* bdef = (const float*)d_in[6];   // [2,30]
  const float* Wff  = (const float*)d_in[7];   // [30,30,3,3]
  const float* bff  = (const float*)d_in[8];   // [30]
  const float* Wp   = (const float*)d_in[9];   // [720,720]
  const float* bp   = (const float*)d_in[10];  // [720]
  float* out = (float*)d_out;

  char* ws = (char*)d_ws;
  const size_t TEN = (size_t)BHW*Gc*sizeof(float);  // 39,720,960 B
  float* mdef = (float*)ws;          // [B,30,H,W]
  float* gi   = (float*)(ws + TEN);  // [B,30,H,W]; offset buffer aliases this
  float* offb = gi;                  // [B,18,H,W] lives before K1 runs

  const int nblkPair = (NPAIR + 255)/256;

  // Multi_Def_Conv: rate 1 then rate 2 (accumulate)
  k_conv3x3<18><<<nblkPair,256,0,stream>>>(x, Woff,        boff,      offb, 1);
  k_deform<<<nblkPair,256,0,stream>>>(x, offb, Wdef,        bdef,      mdef, 1, 1);
  k_conv3x3<18><<<nblkPair,256,0,stream>>>(x, Woff + 4860, boff + 18, offb, 2);
  k_deform<<<nblkPair,256,0,stream>>>(x, offb, Wdef + 8100, bdef + 30, mdef, 2, 0);

  // group_inner (1x1), then softmax-gated fusion in-place on gi
  k_group_inner<<<nblkPair,256,0,stream>>>(x, Wbl, bbl, gi);
  k_gate<<<(BHW+255)/256,256,0,stream>>>(mdef, gi);

  // ff 3x3 conv: gi -> mdef (reuse)
  k_conv3x3<30><<<nblkPair,256,0,stream>>>(gi, Wff, bff, mdef, 1);

  // projection GEMM: out[b,q,n] = sum_p Wp[q,p]*mdef[b,p,n] + bp[q]
  dim3 gp((Wd_+63)/64, (PREN+63)/64, Bz);
  k_proj<<<gp,256,0,stream>>>(mdef, Wp, bp, out);
}

// Round 4
// 2641.506 us; speedup vs baseline: 6.3033x; 6.3033x over previous
//
#include <hip/hip_runtime.h>

// Problem constants
#define Bz 16
#define Gc 30
#define Hs 24
#define Wd_ 862
#define HW (Hs*Wd_)          // 20688
#define BHW (Bz*HW)          // 331008
#define PREN 720

__device__ __forceinline__ int imin(int a,int b){return a<b?a:b;}
__device__ __forceinline__ int imax(int a,int b){return a>b?a:b;}

struct Corners { float m00,m01,m10,m11; int i00,i01,i10,i11; };

__device__ __forceinline__ Corners mk_corners(float py, float px){
  float y0f = floorf(py), x0f = floorf(px);
  float wy = py - y0f, wx = px - x0f;
  int y0 = (int)y0f, x0 = (int)x0f;
  int y1 = y0 + 1, x1 = x0 + 1;
  bool y0i = ((unsigned)y0 < (unsigned)Hs);
  bool y1i = ((unsigned)y1 < (unsigned)Hs);
  bool x0i = ((unsigned)x0 < (unsigned)Wd_);
  bool x1i = ((unsigned)x1 < (unsigned)Wd_);
  float w00=(1.f-wy)*(1.f-wx), w01=(1.f-wy)*wx, w10=wy*(1.f-wx), w11=wy*wx;
  Corners c;
  c.m00 = (y0i&&x0i)?w00:0.f; c.m01=(y0i&&x1i)?w01:0.f;
  c.m10 = (y1i&&x0i)?w10:0.f; c.m11=(y1i&&x1i)?w11:0.f;
  int y0c=imin(imax(y0,0),Hs-1), y1c=imin(imax(y1,0),Hs-1);
  int x0c=imin(imax(x0,0),Wd_-1), x1c=imin(imax(x1,0),Wd_-1);
  c.i00=y0c*Wd_+x0c; c.i01=y0c*Wd_+x1c; c.i10=y1c*Wd_+x0c; c.i11=y1c*Wd_+x1c;
  return c;
}

// ---------------- 3x3 conv, LDS row-staged. grid (7, Hs, Bz), block 256 ----
// block = 128 pixels x 2 output-channel halves
template<int OC, int R>
__global__ __launch_bounds__(256) void k_conv3x3s(
    const float* __restrict__ x, const float* __restrict__ Wo,
    const float* __restrict__ bo, float* __restrict__ out)
{
  constexpr int TILE = 128, SW = TILE + 2*R;
  constexpr int OH = (OC + 1) / 2;
  __shared__ float xs[Gc][3][SW];     // <= 47.5 KB
  __shared__ float w_s[9][OC][Gc];    // <= 32.4 KB
  __shared__ float b_s[OC];

  const int b = blockIdx.z, h = blockIdx.y, w0 = blockIdx.x * TILE;

  for (int i = threadIdx.x; i < 9*OC*Gc; i += 256){
    int ki = i/(OC*Gc), rm = i%(OC*Gc); int o = rm/Gc, c = rm%Gc;
    w_s[ki][o][c] = Wo[(o*Gc + c)*9 + ki];
  }
  if (threadIdx.x < OC) b_s[threadIdx.x] = bo[threadIdx.x];

  const float* xb = x + (size_t)b*Gc*HW;
  for (int i = threadIdx.x; i < Gc*3*SW; i += 256){
    int c = i/(3*SW), rm = i%(3*SW); int rr = rm/SW, ww = rm%SW;
    int hh = h + (rr-1)*R; int wg = w0 + ww - R;
    float v = 0.f;
    if ((unsigned)hh < (unsigned)Hs && (unsigned)wg < (unsigned)Wd_)
      v = xb[(size_t)c*HW + (size_t)hh*Wd_ + wg];
    xs[c][rr][ww] = v;
  }
  __syncthreads();

  const int p = threadIdx.x & 127;   // pixel in tile
  const int q = threadIdx.x >> 7;    // output-channel half (wave-uniform)
  float acc[OH];
  #pragma unroll
  for (int o=0;o<OH;o++) acc[o] = 0.f;

  for (int ki = 0; ki < 9; ki++){
    const int rr = ki/3, dxx = ki%3;
    float xv[Gc];
    #pragma unroll
    for (int c=0;c<Gc;c++) xv[c] = xs[c][rr][p + dxx*R];
    const int ob = q*OH;
    #pragma unroll
    for (int o=0;o<OH;o++){
      if (ob + o < OC){
        float a = acc[o];
        #pragma unroll
        for (int c=0;c<Gc;c++) a += w_s[ki][ob+o][c]*xv[c];
        acc[o] = a;
      }
    }
  }

  const int wpix = w0 + p;
  if (wpix < Wd_){
    float* ob_ = out + (size_t)b*OC*HW + (size_t)h*Wd_ + wpix;
    #pragma unroll
    for (int o=0;o<OH;o++){
      int oo = q*OH + o;
      if (oo < OC) ob_[(size_t)oo*HW] = acc[o] + b_s[oo];
    }
  }
}

// ---------------- deformable conv: 1 px/thread, weights in LDS ------------
template<int R>
__global__ __launch_bounds__(256) void k_deform2(
    const float* __restrict__ x, const float* __restrict__ off,
    const float* __restrict__ Wdf, const float* __restrict__ bd,
    float* __restrict__ out, int first)
{
  __shared__ float w_s[9][Gc][Gc];   // 32.4 KB
  __shared__ float b_s[Gc];
  for (int i = threadIdx.x; i < 9*Gc*Gc; i += 256){
    int ki = i/(Gc*Gc), rm = i%(Gc*Gc); int o = rm/Gc, c = rm%Gc;
    w_s[ki][o][c] = Wdf[(o*Gc + c)*9 + ki];
  }
  if (threadIdx.x < Gc) b_s[threadIdx.x] = bd[threadIdx.x];
  __syncthreads();

  long idx = (long)blockIdx.x*256 + threadIdx.x;
  if (idx >= (long)BHW) return;
  int b = (int)(idx / HW); int s = (int)(idx % HW);
  int h = s / Wd_, w = s % Wd_;
  const float* xb  = x   + (size_t)b*Gc*HW;
  const float* ofb = off + (size_t)b*18*HW + s;

  float acc[Gc];
  #pragma unroll
  for (int o=0;o<Gc;o++) acc[o] = 0.f;

  for (int ki = 0; ki < 9; ki++){
    float oy = ofb[(size_t)(2*ki)*HW];
    float ox = ofb[(size_t)(2*ki+1)*HW];
    Corners cr = mk_corners(oy + (float)(h + (ki/3 - 1)*R),
                            ox + (float)(w + (ki%3 - 1)*R));
    float sv[Gc];
    #pragma unroll
    for (int c=0;c<Gc;c++){
      const float* xc = xb + (size_t)c*HW;
      sv[c] = cr.m00*xc[cr.i00] + cr.m01*xc[cr.i01]
            + cr.m10*xc[cr.i10] + cr.m11*xc[cr.i11];
    }
    #pragma unroll
    for (int o=0;o<Gc;o++){
      float a = acc[o];
      #pragma unroll
      for (int c=0;c<Gc;c++) a += w_s[ki][o][c]*sv[c];
      acc[o] = a;
    }
  }

  float* ob = out + (size_t)b*Gc*HW + s;
  if (first){
    #pragma unroll
    for (int o=0;o<Gc;o++) ob[(size_t)o*HW] = acc[o] + b_s[o];
  } else {
    #pragma unroll
    for (int o=0;o<Gc;o++) ob[(size_t)o*HW] += acc[o] + b_s[o];
  }
}

// ------- fused group_inner (1x1 matvec) + softmax gate, in-place on md ----
__global__ __launch_bounds__(256) void k_gate2(
    const float* __restrict__ x, const float* __restrict__ Wbl,
    const float* __restrict__ bbl, float* __restrict__ md)
{
  __shared__ float w_s[Gc][Gc];
  __shared__ float b_s[Gc];
  for (int i = threadIdx.x; i < Gc*Gc; i += 256)
    w_s[i/Gc][i%Gc] = Wbl[i];
  if (threadIdx.x < Gc) b_s[threadIdx.x] = bbl[threadIdx.x];
  __syncthreads();

  long idx = (long)blockIdx.x*256 + threadIdx.x;
  if (idx >= (long)BHW) return;
  int b = (int)(idx / HW); int s = (int)(idx % HW);
  const float* xp = x  + (size_t)b*Gc*HW + s;
  float*       mp = md + (size_t)b*Gc*HW + s;

  float xv[Gc];
  #pragma unroll
  for (int c=0;c<Gc;c++) xv[c] = xp[(size_t)c*HW];

  float gi[Gc];
  #pragma unroll
  for (int k=0;k<Gc;k++){
    float a = b_s[k];
    #pragma unroll
    for (int c=0;c<Gc;c++) a += w_s[k][c]*xv[c];
    gi[k] = a;
  }

  float v[Gc]; float mx = -1e30f;
  #pragma unroll
  for (int c=0;c<Gc;c++){ v[c] = mp[(size_t)c*HW]; mx = fmaxf(mx, v[c]); }
  float sum = 0.f;
  #pragma unroll
  for (int c=0;c<Gc;c++){ v[c] = __expf(v[c]-mx); sum += v[c]; }
  float inv = 1.f/sum;
  #pragma unroll
  for (int c=0;c<Gc;c++) mp[(size_t)c*HW] = gi[c] + gi[c]*(v[c]*inv);
}

// ---------------- projection GEMM: out[b,q,n] = W[q,p] F[b,p,n] + bias ----
__global__ __launch_bounds__(256) void k_proj(
    const float* __restrict__ F, const float* __restrict__ Wp,
    const float* __restrict__ bp, float* __restrict__ out)
{
  __shared__ float As[16][68];
  __shared__ float Bs[16][64];
  const int b = blockIdx.z;
  const int q0 = blockIdx.y*64;
  const int n0 = blockIdx.x*64;
  const int tid = threadIdx.x;
  const int tm = tid >> 4, tn = tid & 15;
  const int ar = tid >> 4, ac = tid & 15;
  const int br = tid >> 6, bc = tid & 63;
  const float* Fb = F + (size_t)b*PREN*Wd_;
  float acc[4][4] = {};
  for (int k0 = 0; k0 < PREN; k0 += 16){
    #pragma unroll
    for (int i=0;i<4;i++){
      int q = q0 + ar + 16*i;
      As[ac][ar + 16*i] = (q < PREN) ? Wp[(size_t)q*PREN + k0 + ac] : 0.f;
    }
    #pragma unroll
    for (int i=0;i<4;i++){
      int p = k0 + br + 4*i;
      int n = n0 + bc;
      Bs[br + 4*i][bc] = (n < Wd_) ? Fb[(size_t)p*Wd_ + n] : 0.f;
    }
    __syncthreads();
    #pragma unroll
    for (int k=0;k<16;k++){
      float4 a4 = *(const float4*)&As[k][tm*4];
      float4 b4 = *(const float4*)&Bs[k][tn*4];
      float av[4] = {a4.x,a4.y,a4.z,a4.w};
      float bv[4] = {b4.x,b4.y,b4.z,b4.w};
      #pragma unroll
      for (int i=0;i<4;i++)
        #pragma unroll
        for (int j=0;j<4;j++) acc[i][j] += av[i]*bv[j];
    }
    __syncthreads();
  }
  #pragma unroll
  for (int i=0;i<4;i++){
    int q = q0 + tm*4 + i;
    if (q >= PREN) continue;
    float bias = bp[q];
    #pragma unroll
    for (int j=0;j<4;j++){
      int n = n0 + tn*4 + j;
      if (n < Wd_) out[((size_t)b*PREN + q)*Wd_ + n] = acc[i][j] + bias;
    }
  }
}

extern "C" void kernel_launch(void* const* d_in, const int* in_sizes, int n_in,
                              void* d_out, int out_size, void* d_ws, size_t ws_size,
                              hipStream_t stream)
{
  (void)in_sizes; (void)n_in; (void)out_size; (void)ws_size;
  const float* x    = (const float*)d_in[0];
  const float* Wbl  = (const float*)d_in[1];
  const float* bbl  = (const float*)d_in[2];
  const float* Woff = (const float*)d_in[3];   // [2,18,30,3,3]
  const float* boff = (const float*)d_in[4];   // [2,18]
  const float* Wdef = (const float*)d_in[5];   // [2,30,30,3,3]
  const float* bdef = (const float*)d_in[6];   // [2,30]
  const float* Wff  = (const float*)d_in[7];   // [30,30,3,3]
  const float* bff  = (const float*)d_in[8];   // [30]
  const float* Wp   = (const float*)d_in[9];   // [720,720]
  const float* bp   = (const float*)d_in[10];  // [720]
  float* out = (float*)d_out;

  char* ws = (char*)d_ws;
  const size_t TEN = (size_t)BHW*Gc*sizeof(float);  // 39,720,960 B
  float* mdef = (float*)ws;          // [B,30,HW]; becomes repres in-place
  float* offb = (float*)(ws + TEN);  // [B,18,HW] (23.8 MB)
  float* Fbuf = (float*)(ws + TEN);  // ff output [B,30,HW]; offb dead by then

  const dim3 gconv((Wd_ + 127)/128, Hs, Bz);
  const int nblkPx = (BHW + 255)/256;

  // Multi_Def_Conv: rate 1 then rate 2 (accumulate)
  k_conv3x3s<18,1><<<gconv,256,0,stream>>>(x, Woff,        boff,      offb);
  k_deform2<1><<<nblkPx,256,0,stream>>>(x, offb, Wdef,        bdef,      mdef, 1);
  k_conv3x3s<18,2><<<gconv,256,0,stream>>>(x, Woff + 4860,  boff + 18, offb);
  k_deform2<2><<<nblkPx,256,0,stream>>>(x, offb, Wdef + 8100, bdef + 30, mdef, 0);

  // fused group_inner + softmax gate (in-place: mdef -> repres)
  k_gate2<<<nblkPx,256,0,stream>>>(x, Wbl, bbl, mdef);

  // ff 3x3 conv: repres -> Fbuf
  k_conv3x3s<30,1><<<gconv,256,0,stream>>>(mdef, Wff, bff, Fbuf);

  // projection GEMM
  dim3 gp((Wd_+63)/64, (PREN+63)/64, Bz);
  k_proj<<<gp,256,0,stream>>>(Fbuf, Wp, bp, out);
}